// Round 12
// baseline (134.731 us; speedup 1.0000x reference)
//
#include <hip/hip_runtime.h>
#include <hip/hip_bf16.h>

typedef __hip_bfloat16 bf16;
typedef __attribute__((ext_vector_type(8))) short short8v;
typedef __attribute__((ext_vector_type(4))) float f32x4;

#define NSLICE 32   // B*S
#define HW     1024 // H*W
#define CDIM   256  // C1 == C2 == C
#define KVT    32   // kv tokens per flash inner tile

// ---------------------------------------------------------------------------
// Kernel 0: W^T prep. W f32 [cin][cout] -> wt bf16 [mat][cout][cin].
// Wq (mat 0) prescaled by 1/16.
// ---------------------------------------------------------------------------
__global__ __launch_bounds__(256)
void wt_prep_kernel(const float* __restrict__ Wq, const float* __restrict__ Wk,
                    const float* __restrict__ Wv, bf16* __restrict__ wt)
{
    const int m = blockIdx.x >> 8;
    const int r = blockIdx.x & 255;
    const int tid = threadIdx.x;
    const float* W = (m == 0) ? Wq : (m == 1) ? Wk : Wv;
    const float sc = (m == 0) ? 0.0625f : 1.0f;
    wt[((size_t)m << 16) + (size_t)tid * 256 + r] = __float2bfloat16(W[r * 256 + tid] * sc);
}

// ---------------------------------------------------------------------------
// Kernel 1: K + V projection (exact round-9 standalone version).
// ---------------------------------------------------------------------------
__global__ __launch_bounds__(256)
void proj_kv_kernel(const float* __restrict__ dep, const bf16* __restrict__ wt,
                    const float* __restrict__ bk, const float* __restrict__ bv,
                    bf16* __restrict__ ko, bf16* __restrict__ vt)
{
    const int bid   = blockIdx.x;
    const int s     = (bid & 7) * 4 + ((bid >> 3) & 3);
    const int tt    = (bid >> 5) & 15;
    const int chalf = bid >> 9;
    const int t0    = tt * 64;

    const int tid  = threadIdx.x;
    const int wave = tid >> 6;
    const int lane = tid & 63;
    const int lo16 = lane & 15;
    const int hi4  = lane >> 4;
    const int cw0  = chalf * 128 + wave * 32;

    __shared__ short Ad[64][40];

    const int so = tid >> 6, st = tid & 63;
    const float* depS = dep + (size_t)s * CDIM * HW + t0;
    const bf16* wtk = wt + (1 << 16);
    const bf16* wtv = wt + (2 << 16);

    f32x4 ak[2][4], av[4][2];
    #pragma unroll
    for (int a = 0; a < 2; ++a)
        #pragma unroll
        for (int b = 0; b < 4; ++b) {
            ak[a][b] = (f32x4){0.f, 0.f, 0.f, 0.f};
            av[b][a] = (f32x4){0.f, 0.f, 0.f, 0.f};
        }

    float rd[8];
    #pragma unroll
    for (int j = 0; j < 8; ++j) rd[j] = depS[(size_t)(so * 8 + j) * HW + st];

    for (int kc = 0; kc < 8; ++kc) {
        __syncthreads();
        {
            short td[8];
            #pragma unroll
            for (int j = 0; j < 8; ++j) {
                bf16 hb = __float2bfloat16(rd[j]);
                td[j] = *reinterpret_cast<short*>(&hb);
            }
            *reinterpret_cast<short8v*>(&Ad[st][so * 8]) = *reinterpret_cast<short8v*>(td);
        }
        __syncthreads();

        if (kc < 7) {
            #pragma unroll
            for (int j = 0; j < 8; ++j)
                rd[j] = depS[(size_t)((kc + 1) * 32 + so * 8 + j) * HW + st];
        }

        short8v xd[4];
        #pragma unroll
        for (int nf = 0; nf < 4; ++nf)
            xd[nf] = *reinterpret_cast<const short8v*>(&Ad[nf * 16 + lo16][hi4 * 8]);

        const int koff = kc * 32 + hi4 * 8;
        short8v wkf[2], wvf[2];
        #pragma unroll
        for (int mf = 0; mf < 2; ++mf) {
            const size_t wrow = (size_t)(cw0 + mf * 16 + lo16) * 256 + koff;
            wkf[mf] = *reinterpret_cast<const short8v*>(wtk + wrow);
            wvf[mf] = *reinterpret_cast<const short8v*>(wtv + wrow);
        }

        #pragma unroll
        for (int mf = 0; mf < 2; ++mf)
            #pragma unroll
            for (int nf = 0; nf < 4; ++nf)
                ak[mf][nf] = __builtin_amdgcn_mfma_f32_16x16x32_bf16(wkf[mf], xd[nf], ak[mf][nf], 0, 0, 0);
        #pragma unroll
        for (int mf = 0; mf < 4; ++mf)
            #pragma unroll
            for (int nf = 0; nf < 2; ++nf)
                av[mf][nf] = __builtin_amdgcn_mfma_f32_16x16x32_bf16(xd[mf], wvf[nf], av[mf][nf], 0, 0, 0);
    }

    #pragma unroll
    for (int mf = 0; mf < 2; ++mf) {
        const int cb = cw0 + mf * 16 + 4 * hi4;
        const float4 b4 = *reinterpret_cast<const float4*>(bk + cb);
        const float ba[4] = {b4.x, b4.y, b4.z, b4.w};
        #pragma unroll
        for (int nf = 0; nf < 4; ++nf) {
            const int tok = t0 + nf * 16 + lo16;
            bf16 tk[4];
            #pragma unroll
            for (int g = 0; g < 4; ++g)
                tk[g] = __float2bfloat16(ak[mf][nf][g] + ba[g]);
            *reinterpret_cast<uint2*>(&ko[((size_t)s * HW + tok) * CDIM + cb]) =
                *reinterpret_cast<uint2*>(tk);
        }
    }
    #pragma unroll
    for (int nf = 0; nf < 2; ++nf) {
        const int c = cw0 + nf * 16 + lo16;
        const float bvv = bv[c];
        #pragma unroll
        for (int mf = 0; mf < 4; ++mf) {
            const int tb = t0 + mf * 16 + 4 * hi4;
            bf16 tv[4];
            #pragma unroll
            for (int g = 0; g < 4; ++g)
                tv[g] = __float2bfloat16(av[mf][nf][g] + bvv);
            *reinterpret_cast<uint2*>(&vt[((size_t)s * CDIM + c) * HW + tb]) =
                *reinterpret_cast<uint2*>(tv);
        }
    }
}

// ---------------------------------------------------------------------------
// Kernel 2: flash attention with FUSED Q-projection prologue.
// Main loop = exact round-9 structure (KVT=32, no-max softmax, XOR-swizzled
// LDS, register prefetch, setprio). Prologue computes Q = img @ Wq + bq
// in-block (img tile staged to LDS, Wq^T read L2-hot), transposes the MFMA
// D-layout to A-frag layout through a per-wave swizzled LDS region.
// Eliminates the proj_q kernel and the q workspace round-trip.
// ---------------------------------------------------------------------------
__global__ __launch_bounds__(256)
void flash_fusedq_kernel(const float* __restrict__ img, const bf16* __restrict__ wt,
                         const float* __restrict__ bq,
                         const bf16* __restrict__ k, const bf16* __restrict__ vt,
                         float* __restrict__ out)
{
    const int bid = blockIdx.x;
    const int s   = (bid & 7) * 4 + ((bid >> 3) & 3);
    const int t0  = (bid >> 5) * 64;

    const int tid  = threadIdx.x;
    const int wave = tid >> 6;
    const int lane = tid & 63;
    const int lo16 = lane & 15;
    const int hi4  = lane >> 4;

    // 36 KB shared: main loop [0,8192)=K, [8192,16384)=V, [16384,18432)=P.
    // Prologue reuses [0,16384) for the img tile / Q transpose.
    __shared__ __align__(16) short SM[18432];

    const bf16*  kS   = k   + (size_t)s * HW * CDIM;
    const bf16*  vtS  = vt  + (size_t)s * CDIM * HW;
    const float* imgS = img + (size_t)s * CDIM * HW;

    // --- issue K/V tile-0 prefetch early (hides under prologue) ---
    const int krow = tid >> 3;
    const int kch  = tid & 7;
    const int kxor = krow & 7;
    const int vxor = (tid >> 1) & 3;
    short8v kreg[4], vreg[4];
    #pragma unroll
    for (int u = 0; u < 4; ++u) {
        kreg[u] = *reinterpret_cast<const short8v*>(kS + (size_t)krow * CDIM + (kch + 8 * u) * 8);
        vreg[u] = *reinterpret_cast<const short8v*>(vtS + (size_t)tid * HW + u * 8);
    }

    // --- prologue A: stage img tile [tok][cin] bf16, chunk ^= (tok&7) ---
    {
        const int so = tid >> 6, st = tid & 63;
        const float* ip = imgS + t0 + st;
        for (int kc = 0; kc < 8; ++kc) {
            short tw[8];
            #pragma unroll
            for (int j = 0; j < 8; ++j) {
                bf16 hb = __float2bfloat16(ip[(size_t)(kc * 32 + so * 8 + j) * HW]);
                tw[j] = *reinterpret_cast<short*>(&hb);
            }
            const int c  = kc * 4 + so;
            const int cs = (c & ~7) | ((c & 7) ^ (st & 7));
            *reinterpret_cast<short8v*>(&SM[st * 256 + cs * 8]) = *reinterpret_cast<short8v*>(tw);
        }
    }
    __syncthreads();

    // --- prologue B: Q-proj. D[m=cout][n=tok16] = Wq^T @ imgT ---
    f32x4 qacc[16];
    #pragma unroll
    for (int mb = 0; mb < 16; ++mb) qacc[mb] = (f32x4){0.f, 0.f, 0.f, 0.f};
    {
        const int r = wave * 16 + lo16;   // token row in img tile
        for (int kc = 0; kc < 8; ++kc) {
            const int cc  = kc * 4 + hi4;
            const int ccs = (cc & ~7) | ((cc & 7) ^ (lo16 & 7));
            const short8v imgB = *reinterpret_cast<const short8v*>(&SM[r * 256 + ccs * 8]);
            const int koff = kc * 32 + hi4 * 8;
            #pragma unroll
            for (int mb = 0; mb < 16; ++mb) {
                const short8v wq = *reinterpret_cast<const short8v*>(
                    wt + (size_t)(mb * 16 + lo16) * 256 + koff);
                qacc[mb] = __builtin_amdgcn_mfma_f32_16x16x32_bf16(wq, imgB, qacc[mb], 0, 0, 0);
            }
        }
    }
    __syncthreads();   // all img-tile reads complete before overwrite

    // --- prologue C: +bias, bf16, write transposed to per-wave region ---
    {
        short* W = &SM[wave * 4096];
        #pragma unroll
        for (int mb = 0; mb < 16; ++mb) {
            const int cb = mb * 16 + 4 * hi4;
            const float4 b4 = *reinterpret_cast<const float4*>(bq + cb);
            short t4[4];
            {
                bf16 h0 = __float2bfloat16(qacc[mb][0] + b4.x * 0.0625f);
                bf16 h1 = __float2bfloat16(qacc[mb][1] + b4.y * 0.0625f);
                bf16 h2 = __float2bfloat16(qacc[mb][2] + b4.z * 0.0625f);
                bf16 h3 = __float2bfloat16(qacc[mb][3] + b4.w * 0.0625f);
                t4[0] = *reinterpret_cast<short*>(&h0);
                t4[1] = *reinterpret_cast<short*>(&h1);
                t4[2] = *reinterpret_cast<short*>(&h2);
                t4[3] = *reinterpret_cast<short*>(&h3);
            }
            const int c  = mb * 2 + (hi4 >> 1);
            const int cs = (c & ~7) | ((c & 7) ^ (lo16 & 7));
            *reinterpret_cast<uint2*>(&W[lo16 * 256 + cs * 8 + (hi4 & 1) * 4]) =
                *reinterpret_cast<uint2*>(t4);
        }
    }
    __syncthreads();

    // --- prologue D: read Q A-fragments ---
    short8v qf[8];
    {
        const short* R = &SM[wave * 4096];
        #pragma unroll
        for (int ks = 0; ks < 8; ++ks) {
            const int c  = 4 * ks + hi4;
            const int cs = (c & ~7) | ((c & 7) ^ (lo16 & 7));
            qf[ks] = *reinterpret_cast<const short8v*>(&R[lo16 * 256 + cs * 8]);
        }
    }

    f32x4 Oacc[16];
    #pragma unroll
    for (int cf = 0; cf < 16; ++cf) Oacc[cf] = (f32x4){0.f, 0.f, 0.f, 0.f};
    float lp[4] = {0.f, 0.f, 0.f, 0.f};

    const int pvRow = lo16 * 32 + (hi4 ^ ((lo16 >> 1) & 3)) * 8;
    for (int kt = 0; kt < HW / KVT; ++kt) {
        __syncthreads();   // also orders prologue-D reads before first publish
        #pragma unroll
        for (int u = 0; u < 4; ++u)
            *reinterpret_cast<short8v*>(&SM[krow * 256 + ((kch ^ kxor) + 8 * u) * 8]) = kreg[u];
        #pragma unroll
        for (int u = 0; u < 4; ++u)
            *reinterpret_cast<short8v*>(&SM[8192 + tid * 32 + (u ^ vxor) * 8]) = vreg[u];
        __syncthreads();

        if (kt + 1 < HW / KVT) {
            const bf16* src = kS + (size_t)(kt + 1) * KVT * CDIM;
            #pragma unroll
            for (int u = 0; u < 4; ++u) {
                kreg[u] = *reinterpret_cast<const short8v*>(src + (size_t)krow * CDIM + (kch + 8 * u) * 8);
                vreg[u] = *reinterpret_cast<const short8v*>(vtS + (size_t)tid * HW + (kt + 1) * KVT + u * 8);
            }
        }

        // ---- QK^T ----
        f32x4 sa[2];
        sa[0] = (f32x4){0.f, 0.f, 0.f, 0.f};
        sa[1] = (f32x4){0.f, 0.f, 0.f, 0.f};
        __builtin_amdgcn_s_setprio(1);
        #pragma unroll
        for (int ks = 0; ks < 8; ++ks) {
            #pragma unroll
            for (int cf = 0; cf < 2; ++cf) {
                const int row = cf * 16 + lo16;
                short8v bfr = *reinterpret_cast<const short8v*>(
                    &SM[row * 256 + ((4 * ks + hi4) ^ (lo16 & 7)) * 8]);
                sa[cf] = __builtin_amdgcn_mfma_f32_16x16x32_bf16(qf[ks], bfr, sa[cf], 0, 0, 0);
            }
        }
        __builtin_amdgcn_s_setprio(0);

        // ---- P = exp(S); lane-local l partials; P -> LDS swizzled ----
        #pragma unroll
        for (int cf = 0; cf < 2; ++cf)
            #pragma unroll
            for (int g = 0; g < 4; ++g) {
                const float e = __expf(sa[cf][g]);
                lp[g] += e;
                bf16 hb = __float2bfloat16(e);
                const int r = 4 * hi4 + g;
                const int ch = (2 * cf + (lo16 >> 3)) ^ ((r >> 1) & 3);
                SM[16384 + wave * 512 + r * 32 + ch * 8 + (lo16 & 7)] = *reinterpret_cast<short*>(&hb);
            }

        const short8v pa = *reinterpret_cast<const short8v*>(&SM[16384 + wave * 512 + pvRow]);

        // ---- PV ----
        __builtin_amdgcn_s_setprio(1);
        #pragma unroll
        for (int cf = 0; cf < 16; ++cf) {
            const int row = cf * 16 + lo16;
            const short8v vb = *reinterpret_cast<const short8v*>(
                &SM[8192 + row * 32 + (hi4 ^ ((lo16 >> 1) & 3)) * 8]);
            Oacc[cf] = __builtin_amdgcn_mfma_f32_16x16x32_bf16(pa, vb, Oacc[cf], 0, 0, 0);
        }
        __builtin_amdgcn_s_setprio(0);
    }

    // ---- epilogue ----
    float inv[4];
    #pragma unroll
    for (int g = 0; g < 4; ++g) {
        float l = lp[g];
        #pragma unroll
        for (int off = 1; off < 16; off <<= 1) l += __shfl_xor(l, off);
        inv[g] = 1.0f / l;
    }
    float* outS = out + (size_t)s * CDIM * HW;
    const int tt = t0 + wave * 16 + 4 * hi4;
    #pragma unroll
    for (int cf = 0; cf < 16; ++cf) {
        const int c = cf * 16 + lo16;
        const float4 r4 = *reinterpret_cast<const float4*>(imgS + (size_t)c * HW + tt);
        float4 o;
        o.x = Oacc[cf][0] * inv[0] + r4.x;
        o.y = Oacc[cf][1] * inv[1] + r4.y;
        o.z = Oacc[cf][2] * inv[2] + r4.z;
        o.w = Oacc[cf][3] * inv[3] + r4.w;
        *reinterpret_cast<float4*>(outS + (size_t)c * HW + tt) = o;
    }
}

// ---------------------------------------------------------------------------
extern "C" void kernel_launch(void* const* d_in, const int* in_sizes, int n_in,
                              void* d_out, int out_size, void* d_ws, size_t ws_size,
                              hipStream_t stream)
{
    const float* img = (const float*)d_in[0];
    const float* dep = (const float*)d_in[1];
    const float* Wq  = (const float*)d_in[2];
    const float* bq  = (const float*)d_in[3];
    const float* Wk  = (const float*)d_in[4];
    const float* bk  = (const float*)d_in[5];
    const float* Wv  = (const float*)d_in[6];
    const float* bv  = (const float*)d_in[7];
    float* out = (float*)d_out;

    const size_t npt  = (size_t)NSLICE * HW * CDIM;
    const size_t need = 3 * npt * sizeof(bf16) + 3 * 65536 * sizeof(bf16);
    if (ws_size < need) {
        hipMemsetAsync(d_out, 0, (size_t)out_size * sizeof(float), stream);
        return;
    }

    bf16* q  = (bf16*)d_ws;        // (unused now; layout kept stable)
    bf16* k  = q + npt;            // token-major
    bf16* vt = k + npt;            // channel-major
    bf16* wt = vt + npt;           // [3][256][256] W^T

    wt_prep_kernel<<<dim3(3 * 256), 256, 0, stream>>>(Wq, Wk, Wv, wt);

    proj_kv_kernel<<<dim3(NSLICE * 32), 256, 0, stream>>>(dep, wt, bk, bv, k, vt);

    flash_fusedq_kernel<<<dim3(NSLICE * 16), 256, 0, stream>>>(img, wt, bq, k, vt, out);
}

// Round 13
// 132.477 us; speedup vs baseline: 1.0170x; 1.0170x over previous
//
#include <hip/hip_runtime.h>
#include <hip/hip_bf16.h>

typedef __hip_bfloat16 bf16;
typedef __attribute__((ext_vector_type(8))) short short8v;
typedef __attribute__((ext_vector_type(4))) float f32x4;

#define NSLICE 32   // B*S
#define HW     1024 // H*W
#define CDIM   256  // C1 == C2 == C
#define KVT    32   // kv tokens per flash inner tile

// ---------------------------------------------------------------------------
// Kernel 0: W^T prep. W f32 [cin][cout] -> wt bf16 [mat][cout][cin].
// Wq (mat 0) prescaled by 1/16.
// ---------------------------------------------------------------------------
__global__ __launch_bounds__(256)
void wt_prep_kernel(const float* __restrict__ Wq, const float* __restrict__ Wk,
                    const float* __restrict__ Wv, bf16* __restrict__ wt)
{
    const int m = blockIdx.x >> 8;
    const int r = blockIdx.x & 255;
    const int tid = threadIdx.x;
    const float* W = (m == 0) ? Wq : (m == 1) ? Wk : Wv;
    const float sc = (m == 0) ? 0.0625f : 1.0f;
    wt[((size_t)m << 16) + (size_t)tid * 256 + r] = __float2bfloat16(W[r * 256 + tid] * sc);
}

// ---------------------------------------------------------------------------
// Kernel 1a: Q projection (exact round-9 version).
// ---------------------------------------------------------------------------
__global__ __launch_bounds__(256)
void proj_q_kernel(const float* __restrict__ img, const bf16* __restrict__ wt,
                   const float* __restrict__ bq, bf16* __restrict__ qo)
{
    const int bid   = blockIdx.x;
    const int s     = (bid & 7) * 4 + ((bid >> 3) & 3);
    const int tt    = (bid >> 5) & 15;
    const int chalf = bid >> 9;
    const int t0    = tt * 64;

    const int tid  = threadIdx.x;
    const int wave = tid >> 6;
    const int lane = tid & 63;
    const int lo16 = lane & 15;
    const int hi4  = lane >> 4;
    const int cw0  = chalf * 128 + wave * 32;

    __shared__ short Ai[64][40];

    const int so = tid >> 6, st = tid & 63;
    const float* imgS = img + (size_t)s * CDIM * HW + t0;

    f32x4 aq[2][4];
    #pragma unroll
    for (int a = 0; a < 2; ++a)
        #pragma unroll
        for (int b = 0; b < 4; ++b) aq[a][b] = (f32x4){0.f, 0.f, 0.f, 0.f};

    float ri[8];
    #pragma unroll
    for (int j = 0; j < 8; ++j) ri[j] = imgS[(size_t)(so * 8 + j) * HW + st];

    for (int kc = 0; kc < 8; ++kc) {
        __syncthreads();
        {
            short ti[8];
            #pragma unroll
            for (int j = 0; j < 8; ++j) {
                bf16 hb = __float2bfloat16(ri[j]);
                ti[j] = *reinterpret_cast<short*>(&hb);
            }
            *reinterpret_cast<short8v*>(&Ai[st][so * 8]) = *reinterpret_cast<short8v*>(ti);
        }
        __syncthreads();

        if (kc < 7) {
            #pragma unroll
            for (int j = 0; j < 8; ++j)
                ri[j] = imgS[(size_t)((kc + 1) * 32 + so * 8 + j) * HW + st];
        }

        short8v xi[4];
        #pragma unroll
        for (int nf = 0; nf < 4; ++nf)
            xi[nf] = *reinterpret_cast<const short8v*>(&Ai[nf * 16 + lo16][hi4 * 8]);

        const int koff = kc * 32 + hi4 * 8;
        short8v wqf[2];
        #pragma unroll
        for (int mf = 0; mf < 2; ++mf)
            wqf[mf] = *reinterpret_cast<const short8v*>(
                wt + (size_t)(cw0 + mf * 16 + lo16) * 256 + koff);

        #pragma unroll
        for (int mf = 0; mf < 2; ++mf)
            #pragma unroll
            for (int nf = 0; nf < 4; ++nf)
                aq[mf][nf] = __builtin_amdgcn_mfma_f32_16x16x32_bf16(wqf[mf], xi[nf], aq[mf][nf], 0, 0, 0);
    }

    #pragma unroll
    for (int mf = 0; mf < 2; ++mf) {
        const int cb = cw0 + mf * 16 + 4 * hi4;
        const float4 b4 = *reinterpret_cast<const float4*>(bq + cb);
        const float ba[4] = {b4.x * 0.0625f, b4.y * 0.0625f, b4.z * 0.0625f, b4.w * 0.0625f};
        #pragma unroll
        for (int nf = 0; nf < 4; ++nf) {
            const int tok = t0 + nf * 16 + lo16;
            bf16 tq[4];
            #pragma unroll
            for (int g = 0; g < 4; ++g)
                tq[g] = __float2bfloat16(aq[mf][nf][g] + ba[g]);
            *reinterpret_cast<uint2*>(&qo[((size_t)s * HW + tok) * CDIM + cb]) =
                *reinterpret_cast<uint2*>(tq);
        }
    }
}

// ---------------------------------------------------------------------------
// Kernel 1b: K + V projection (exact round-9 version).
// ---------------------------------------------------------------------------
__global__ __launch_bounds__(256)
void proj_kv_kernel(const float* __restrict__ dep, const bf16* __restrict__ wt,
                    const float* __restrict__ bk, const float* __restrict__ bv,
                    bf16* __restrict__ ko, bf16* __restrict__ vt)
{
    const int bid   = blockIdx.x;
    const int s     = (bid & 7) * 4 + ((bid >> 3) & 3);
    const int tt    = (bid >> 5) & 15;
    const int chalf = bid >> 9;
    const int t0    = tt * 64;

    const int tid  = threadIdx.x;
    const int wave = tid >> 6;
    const int lane = tid & 63;
    const int lo16 = lane & 15;
    const int hi4  = lane >> 4;
    const int cw0  = chalf * 128 + wave * 32;

    __shared__ short Ad[64][40];

    const int so = tid >> 6, st = tid & 63;
    const float* depS = dep + (size_t)s * CDIM * HW + t0;
    const bf16* wtk = wt + (1 << 16);
    const bf16* wtv = wt + (2 << 16);

    f32x4 ak[2][4], av[4][2];
    #pragma unroll
    for (int a = 0; a < 2; ++a)
        #pragma unroll
        for (int b = 0; b < 4; ++b) {
            ak[a][b] = (f32x4){0.f, 0.f, 0.f, 0.f};
            av[b][a] = (f32x4){0.f, 0.f, 0.f, 0.f};
        }

    float rd[8];
    #pragma unroll
    for (int j = 0; j < 8; ++j) rd[j] = depS[(size_t)(so * 8 + j) * HW + st];

    for (int kc = 0; kc < 8; ++kc) {
        __syncthreads();
        {
            short td[8];
            #pragma unroll
            for (int j = 0; j < 8; ++j) {
                bf16 hb = __float2bfloat16(rd[j]);
                td[j] = *reinterpret_cast<short*>(&hb);
            }
            *reinterpret_cast<short8v*>(&Ad[st][so * 8]) = *reinterpret_cast<short8v*>(td);
        }
        __syncthreads();

        if (kc < 7) {
            #pragma unroll
            for (int j = 0; j < 8; ++j)
                rd[j] = depS[(size_t)((kc + 1) * 32 + so * 8 + j) * HW + st];
        }

        short8v xd[4];
        #pragma unroll
        for (int nf = 0; nf < 4; ++nf)
            xd[nf] = *reinterpret_cast<const short8v*>(&Ad[nf * 16 + lo16][hi4 * 8]);

        const int koff = kc * 32 + hi4 * 8;
        short8v wkf[2], wvf[2];
        #pragma unroll
        for (int mf = 0; mf < 2; ++mf) {
            const size_t wrow = (size_t)(cw0 + mf * 16 + lo16) * 256 + koff;
            wkf[mf] = *reinterpret_cast<const short8v*>(wtk + wrow);
            wvf[mf] = *reinterpret_cast<const short8v*>(wtv + wrow);
        }

        #pragma unroll
        for (int mf = 0; mf < 2; ++mf)
            #pragma unroll
            for (int nf = 0; nf < 4; ++nf)
                ak[mf][nf] = __builtin_amdgcn_mfma_f32_16x16x32_bf16(wkf[mf], xd[nf], ak[mf][nf], 0, 0, 0);
        #pragma unroll
        for (int mf = 0; mf < 4; ++mf)
            #pragma unroll
            for (int nf = 0; nf < 2; ++nf)
                av[mf][nf] = __builtin_amdgcn_mfma_f32_16x16x32_bf16(xd[mf], wvf[nf], av[mf][nf], 0, 0, 0);
    }

    #pragma unroll
    for (int mf = 0; mf < 2; ++mf) {
        const int cb = cw0 + mf * 16 + 4 * hi4;
        const float4 b4 = *reinterpret_cast<const float4*>(bk + cb);
        const float ba[4] = {b4.x, b4.y, b4.z, b4.w};
        #pragma unroll
        for (int nf = 0; nf < 4; ++nf) {
            const int tok = t0 + nf * 16 + lo16;
            bf16 tk[4];
            #pragma unroll
            for (int g = 0; g < 4; ++g)
                tk[g] = __float2bfloat16(ak[mf][nf][g] + ba[g]);
            *reinterpret_cast<uint2*>(&ko[((size_t)s * HW + tok) * CDIM + cb]) =
                *reinterpret_cast<uint2*>(tk);
        }
    }
    #pragma unroll
    for (int nf = 0; nf < 2; ++nf) {
        const int c = cw0 + nf * 16 + lo16;
        const float bvv = bv[c];
        #pragma unroll
        for (int mf = 0; mf < 4; ++mf) {
            const int tb = t0 + mf * 16 + 4 * hi4;
            bf16 tv[4];
            #pragma unroll
            for (int g = 0; g < 4; ++g)
                tv[g] = __float2bfloat16(av[mf][nf][g] + bvv);
            *reinterpret_cast<uint2*>(&vt[((size_t)s * CDIM + c) * HW + tb]) =
                *reinterpret_cast<uint2*>(tv);
        }
    }
}

// ---------------------------------------------------------------------------
// Kernel 2: MFMA flash, M=32 rows/wave (2 fragment sets). Each K/V B-frag
// LDS read now feeds 2 MFMAs -> LDS instr per MFMA drops 1.53 -> 0.9.
// Everything else identical to round 9: KVT=32, no-max softmax, XOR-swizzled
// LDS, register prefetch, setprio. Block = 4 waves x 32 rows = 128 q-rows.
// ---------------------------------------------------------------------------
__global__ __launch_bounds__(256)
void flash_mfma_kernel(const bf16* __restrict__ q, const bf16* __restrict__ k,
                       const bf16* __restrict__ vt, const float* __restrict__ img,
                       float* __restrict__ out)
{
    const int bid = blockIdx.x;
    const int s   = (bid & 7) * 4 + ((bid >> 3) & 3);
    const int t0  = (bid >> 5) * 128;

    const int tid  = threadIdx.x;
    const int wave = tid >> 6;
    const int lane = tid & 63;
    const int lo16 = lane & 15;
    const int hi4  = lane >> 4;

    __shared__ short KsL[32 * 256];      // 16 KB, chunk ^= (row&7)
    __shared__ short VsL[256 * 32];      // 16 KB, chunk ^= ((row>>1)&3)
    __shared__ short PsL[4 * 2 * 512];   // 8 KB: [wave][mset][16][32] swizzled

    const int rowbase = t0 + wave * 32;

    short8v qf[2][8];
    #pragma unroll
    for (int m = 0; m < 2; ++m) {
        const bf16* qp = q + ((size_t)s * HW + rowbase + m * 16 + lo16) * CDIM + hi4 * 8;
        #pragma unroll
        for (int kf = 0; kf < 8; ++kf)
            qf[m][kf] = *reinterpret_cast<const short8v*>(qp + kf * 32);
    }

    f32x4 Oa[16], Ob[16];
    #pragma unroll
    for (int cf = 0; cf < 16; ++cf) {
        Oa[cf] = (f32x4){0.f, 0.f, 0.f, 0.f};
        Ob[cf] = (f32x4){0.f, 0.f, 0.f, 0.f};
    }
    float lp[2][4] = {{0.f, 0.f, 0.f, 0.f}, {0.f, 0.f, 0.f, 0.f}};

    const bf16* kS  = k  + (size_t)s * HW * CDIM;
    const bf16* vtS = vt + (size_t)s * CDIM * HW;

    const int krow = tid >> 3;
    const int kch  = tid & 7;
    const int kxor = krow & 7;
    const int vxor = (tid >> 1) & 3;

    short8v kreg[4], vreg[4];
    #pragma unroll
    for (int u = 0; u < 4; ++u) {
        kreg[u] = *reinterpret_cast<const short8v*>(kS + (size_t)krow * CDIM + (kch + 8 * u) * 8);
        vreg[u] = *reinterpret_cast<const short8v*>(vtS + (size_t)tid * HW + u * 8);
    }

    const int pvRow = lo16 * 32 + (hi4 ^ ((lo16 >> 1) & 3)) * 8;
    for (int kt = 0; kt < HW / KVT; ++kt) {
        __syncthreads();
        #pragma unroll
        for (int u = 0; u < 4; ++u)
            *reinterpret_cast<short8v*>(&KsL[krow * 256 + ((kch ^ kxor) + 8 * u) * 8]) = kreg[u];
        #pragma unroll
        for (int u = 0; u < 4; ++u)
            *reinterpret_cast<short8v*>(&VsL[tid * 32 + (u ^ vxor) * 8]) = vreg[u];
        __syncthreads();

        if (kt + 1 < HW / KVT) {
            const bf16* src = kS + (size_t)(kt + 1) * KVT * CDIM;
            #pragma unroll
            for (int u = 0; u < 4; ++u) {
                kreg[u] = *reinterpret_cast<const short8v*>(src + (size_t)krow * CDIM + (kch + 8 * u) * 8);
                vreg[u] = *reinterpret_cast<const short8v*>(vtS + (size_t)tid * HW + (kt + 1) * KVT + u * 8);
            }
        }

        // ---- QK^T: one B-frag read feeds both msets ----
        f32x4 sa[2][2];
        sa[0][0] = (f32x4){0.f, 0.f, 0.f, 0.f};
        sa[0][1] = (f32x4){0.f, 0.f, 0.f, 0.f};
        sa[1][0] = (f32x4){0.f, 0.f, 0.f, 0.f};
        sa[1][1] = (f32x4){0.f, 0.f, 0.f, 0.f};
        __builtin_amdgcn_s_setprio(1);
        #pragma unroll
        for (int ks = 0; ks < 8; ++ks) {
            #pragma unroll
            for (int cf = 0; cf < 2; ++cf) {
                const int row = cf * 16 + lo16;
                const short8v bfr = *reinterpret_cast<const short8v*>(
                    &KsL[row * 256 + ((4 * ks + hi4) ^ (lo16 & 7)) * 8]);
                sa[0][cf] = __builtin_amdgcn_mfma_f32_16x16x32_bf16(qf[0][ks], bfr, sa[0][cf], 0, 0, 0);
                sa[1][cf] = __builtin_amdgcn_mfma_f32_16x16x32_bf16(qf[1][ks], bfr, sa[1][cf], 0, 0, 0);
            }
        }
        __builtin_amdgcn_s_setprio(0);

        // ---- P = exp(S); lane-local l partials; P -> LDS swizzled ----
        #pragma unroll
        for (int m = 0; m < 2; ++m)
            #pragma unroll
            for (int cf = 0; cf < 2; ++cf)
                #pragma unroll
                for (int g = 0; g < 4; ++g) {
                    const float e = __expf(sa[m][cf][g]);
                    lp[m][g] += e;
                    bf16 hb = __float2bfloat16(e);
                    const int r = 4 * hi4 + g;
                    const int ch = (2 * cf + (lo16 >> 3)) ^ ((r >> 1) & 3);
                    PsL[wave * 1024 + m * 512 + r * 32 + ch * 8 + (lo16 & 7)] =
                        *reinterpret_cast<short*>(&hb);
                }

        const short8v pa0 = *reinterpret_cast<const short8v*>(&PsL[wave * 1024 + pvRow]);
        const short8v pa1 = *reinterpret_cast<const short8v*>(&PsL[wave * 1024 + 512 + pvRow]);

        // ---- PV: one V B-frag read feeds both msets ----
        __builtin_amdgcn_s_setprio(1);
        #pragma unroll
        for (int cf = 0; cf < 16; ++cf) {
            const int row = cf * 16 + lo16;
            const short8v vb = *reinterpret_cast<const short8v*>(
                &VsL[row * 32 + (hi4 ^ ((lo16 >> 1) & 3)) * 8]);
            Oa[cf] = __builtin_amdgcn_mfma_f32_16x16x32_bf16(pa0, vb, Oa[cf], 0, 0, 0);
            Ob[cf] = __builtin_amdgcn_mfma_f32_16x16x32_bf16(pa1, vb, Ob[cf], 0, 0, 0);
        }
        __builtin_amdgcn_s_setprio(0);
    }

    // ---- epilogue ----
    const float* imgS = img + (size_t)s * CDIM * HW;
    float*       outS = out + (size_t)s * CDIM * HW;
    #pragma unroll
    for (int m = 0; m < 2; ++m) {
        float inv[4];
        #pragma unroll
        for (int g = 0; g < 4; ++g) {
            float l = lp[m][g];
            #pragma unroll
            for (int off = 1; off < 16; off <<= 1) l += __shfl_xor(l, off);
            inv[g] = 1.0f / l;
        }
        const int tt = rowbase + m * 16 + 4 * hi4;
        #pragma unroll
        for (int cf = 0; cf < 16; ++cf) {
            const int c = cf * 16 + lo16;
            const f32x4 O = (m == 0) ? Oa[cf] : Ob[cf];
            const float4 r4 = *reinterpret_cast<const float4*>(imgS + (size_t)c * HW + tt);
            float4 o;
            o.x = O[0] * inv[0] + r4.x;
            o.y = O[1] * inv[1] + r4.y;
            o.z = O[2] * inv[2] + r4.z;
            o.w = O[3] * inv[3] + r4.w;
            *reinterpret_cast<float4*>(outS + (size_t)c * HW + tt) = o;
        }
    }
}

// ---------------------------------------------------------------------------
extern "C" void kernel_launch(void* const* d_in, const int* in_sizes, int n_in,
                              void* d_out, int out_size, void* d_ws, size_t ws_size,
                              hipStream_t stream)
{
    const float* img = (const float*)d_in[0];
    const float* dep = (const float*)d_in[1];
    const float* Wq  = (const float*)d_in[2];
    const float* bq  = (const float*)d_in[3];
    const float* Wk  = (const float*)d_in[4];
    const float* bk  = (const float*)d_in[5];
    const float* Wv  = (const float*)d_in[6];
    const float* bv  = (const float*)d_in[7];
    float* out = (float*)d_out;

    const size_t npt  = (size_t)NSLICE * HW * CDIM;
    const size_t need = 3 * npt * sizeof(bf16) + 3 * 65536 * sizeof(bf16);
    if (ws_size < need) {
        hipMemsetAsync(d_out, 0, (size_t)out_size * sizeof(float), stream);
        return;
    }

    bf16* q  = (bf16*)d_ws;        // token-major, prescaled
    bf16* k  = q + npt;            // token-major
    bf16* vt = k + npt;            // channel-major
    bf16* wt = vt + npt;           // [3][256][256] W^T

    wt_prep_kernel<<<dim3(3 * 256), 256, 0, stream>>>(Wq, Wk, Wv, wt);

    proj_q_kernel<<<dim3(NSLICE * 32), 256, 0, stream>>>(img, wt, bq, q);
    proj_kv_kernel<<<dim3(NSLICE * 32), 256, 0, stream>>>(dep, wt, bk, bv, k, vt);

    flash_mfma_kernel<<<dim3(NSLICE * 8), 256, 0, stream>>>(q, k, vt, img, out);
}